// Round 5
// baseline (311.437 us; speedup 1.0000x reference)
//
#include <hip/hip_runtime.h>
#include <hip/hip_bf16.h>

// MultiScaleFeatureExtractor on MI355X (gfx950) — Round 11
// Math restructuring (unchanged):
//   logits = x @ (Wx@Wslice) + (bx@Wslice + bslice)      (px never materialized)
//   out[s,d] = (sum_n w[n,s]*fx[n,d]) / (sum_n w[n,s] + 0.01)
// R11 vs R9/R10 (correctness recovery + honest bisection):
//   - R9 and R10 failed BIT-IDENTICALLY (absmax 1.205811 / 468.0) despite
//     different softmax reduces -> DPP was innocent; the shared changes were
//     the b128 staging remap (algebra re-verified element-by-element, yet
//     convicted by elimination -- likely a codegen-level issue with the
//     uint4v ds_write_b128 path) and the bias*invt prefold (exact algebra).
//   - R11 = R8 main VERBATIM (R8 staging uint2v/b64, shfl_xor reduce), plus
//     only: (a) bias*invt prefold (finishes the bisection: pass => remap was
//     the bug), (b) v_rcp for the softmax divides (<=1ulp), (c) s_setprio(1)
//     around MFMA clusters (pure hint; role-split waves + 2 blocks/CU is the
//     regime where it measured +4-7%).
//
// ws layout (NEED = 792,576 B):
//   [0,      524288)  WtF  bf16 B-frags [proj(2)][head(8)][nt(4)][ks(8)][lane(64)][j(8)]
//   [524288, 526336)  bc   f32 [512]
//   [526336, 788480)  Tg   f32 [B*8*64*64]
//   [788480, 792576)  ng   f32 [B*8*64]

typedef __attribute__((ext_vector_type(8))) short short8;
typedef __attribute__((ext_vector_type(4))) short short4v;
typedef __attribute__((ext_vector_type(4))) float float4v;
typedef __attribute__((ext_vector_type(2))) unsigned int uint2v;

#define MP 36        // wT/fT pitch: 32-token rows + 4 pad shorts (R4 measured 0 conflicts)
#define XP 264       // XS pitch in shorts: 528B rows (16B multiple; l16-lane frag reads 2-way = free)

__device__ __forceinline__ unsigned short f2bf(float f) {
    union { float f; unsigned int u; } v; v.f = f;
    unsigned int r = (v.u + 0x7FFFu + ((v.u >> 16) & 1u)) >> 16;  // RNE
    return (unsigned short)r;
}

__device__ __forceinline__ unsigned int pack2(float a, float b) {
    __hip_bfloat162 h = __float22bfloat162_rn(float2{a, b});
    union { __hip_bfloat162 h; unsigned int u; } cv; cv.h = h;
    return cv.u;   // low 16 = a, high 16 = b
}

// ---- prep4: fold Wx@Wslice + reformat Wfx into B-frag order; compute bc. (R6, unchanged)
__global__ __launch_bounds__(256)
void msfe_prep4(const float* __restrict__ Wx, const float* __restrict__ bx,
                const float* __restrict__ Wfx,
                const float* __restrict__ Wslice, const float* __restrict__ bslice,
                unsigned short* __restrict__ WtF, float* __restrict__ bcv) {
    const int b = blockIdx.x, t = threadIdx.x;
    if (b < 256) {
        const int head = b >> 5, oct = b & 31;
        __shared__ float Wsl[64 * 65];          // [d][s] +1 pad
        __shared__ float WxS[8 * 64];           // [j][d]
        __shared__ unsigned short stg[8 * 64];  // [j][s]
        #pragma unroll
        for (int i = 0; i < 16; ++i) {          // Wslice: 4096 floats, coalesced
            int idx = i * 256 + t; int d = idx >> 6, s = idx & 63;
            Wsl[d * 65 + s] = Wslice[idx];
        }
        #pragma unroll
        for (int i = 0; i < 2; ++i) {           // 8 Wx rows x 64 ch, coalesced 256B rows
            int idx = i * 256 + t; int j = idx >> 6, d = idx & 63;
            WxS[j * 64 + d] = Wx[(long)(oct * 8 + j) * 512 + head * 64 + d];
        }
        __syncthreads();
        const int s = t & 63;
        #pragma unroll
        for (int rep = 0; rep < 2; ++rep) {
            int j = (t >> 6) + rep * 4;         // wave-uniform j
            float a0 = 0.f, a1 = 0.f, a2 = 0.f, a3 = 0.f;
            #pragma unroll
            for (int d = 0; d < 64; d += 4) {   // WxS broadcast (free), Wsl 2-way (free)
                a0 += WxS[j * 64 + d]     * Wsl[(d)     * 65 + s];
                a1 += WxS[j * 64 + d + 1] * Wsl[(d + 1) * 65 + s];
                a2 += WxS[j * 64 + d + 2] * Wsl[(d + 2) * 65 + s];
                a3 += WxS[j * 64 + d + 3] * Wsl[(d + 3) * 65 + s];
            }
            stg[j * 64 + s] = f2bf((a0 + a1) + (a2 + a3));
        }
        __syncthreads();
        if (t < 64) {
            int nt = t >> 4, l16 = t & 15;
            int ks = oct >> 2, quad = oct & 3;
            int lane = quad * 16 + l16;
            short8 o;
            #pragma unroll
            for (int j = 0; j < 8; ++j) o[j] = (short)stg[j * 64 + nt * 16 + l16];
            *(short8*)(WtF + ((((long)(0 * 8 + head) * 4 + nt) * 8 + ks) * 64 + lane) * 8) = o;
        }
    } else if (b < 320) {
        const int head = (b - 256) >> 3, ks = (b - 256) & 7;
        const int nt = t >> 6, lane = t & 63;
        const int quad = lane >> 4, l16 = lane & 15;
        short8 o;
        #pragma unroll
        for (int j = 0; j < 8; ++j)             // 4x64B segments per instr
            o[j] = (short)f2bf(Wfx[(long)(ks * 32 + quad * 8 + j) * 512 + head * 64 + nt * 16 + l16]);
        *(short8*)(WtF + ((((long)(1 * 8 + head) * 4 + nt) * 8 + ks) * 64 + lane) * 8) = o;
    } else {
        #pragma unroll
        for (int p = 0; p < 2; ++p) {
            int j = t + p * 256;
            int h = j >> 6, s = j & 63;
            float bsum = bslice[s];
            for (int d = 0; d < 64; ++d) bsum += bx[h * 64 + d] * Wslice[d * 64 + s];
            bcv[j] = bsum;
        }
    }
}

// ---- main9: 2048 blocks x 256 thr (4 waves), 512-token tiles, 16 x 32-token chunks.
// Weights pinned in AGPRs ("+a"); x staged fp32->bf16 in-block (R8 staging, verbatim).
// R11 deltas: bias*invt prefold, v_rcp divides, s_setprio around MFMA clusters.
__global__ __launch_bounds__(256, 2)
void msfe_main9(const float* __restrict__ x,
                const unsigned short* __restrict__ WtF,
                const float* __restrict__ bcv,
                const float* __restrict__ bfx,
                const float* __restrict__ temperature,
                float* __restrict__ Tg, float* __restrict__ ng) {
    __shared__ unsigned short wT[2][64 * MP];              // [s][token] bf16, double-buffered
    __shared__ unsigned short fT[2][64 * MP];              // [d][token]
    __shared__ __align__(16) unsigned short XS[2][32 * XP];// [token][ch] bf16 x-stage, dbuf

    const int tid  = threadIdx.x;
    const int lane = tid & 63;
    const int wv   = tid >> 6;    // 0..3
    const int quad = lane >> 4;
    const int l16  = lane & 15;

    // swizzle: a tile's 8 head-blocks land on one XCD in the same dispatch round
    const int bidx = blockIdx.x;                     // 0..2047
    const int tile = (bidx >> 6) * 8 + (bidx & 7);   // 0..255 (512 tokens each)
    const int head = (bidx >> 3) & 7;
    const int batch = tile >> 7;

    const int proj = wv >> 1;   // waves 0,1: logits+softmax; 2,3: fx
    const int tw   = wv & 1;    // 16-token sub-tile within 32-token chunk

    // ---- weight fragments -> AGPRs, pinned (R6: "+a" leaves VGPRs for loads).
    short8 wfr[4][8];
    {
        const unsigned short* wb = WtF + (((long)(proj * 8 + head) * 4) * 8) * 512 + (long)lane * 8;
        #pragma unroll
        for (int nt = 0; nt < 4; ++nt)
            #pragma unroll
            for (int ks = 0; ks < 8; ++ks)
                wfr[nt][ks] = *(const short8*)(wb + (nt * 8 + ks) * 512);
    }
    #pragma unroll
    for (int nt = 0; nt < 4; ++nt)
        #pragma unroll
        for (int ks = 0; ks < 8; ++ks)
            asm volatile("" : "+a"(wfr[nt][ks]));

    float tmp = temperature[head];
    tmp = fminf(fmaxf(tmp, 0.5f), 5.0f);
    const float invt = 1.0f / tmp;

    float bias[4];
    #pragma unroll
    for (int nt = 0; nt < 4; ++nt)
        bias[nt] = (proj == 0 ? bcv : bfx)[head * 64 + nt * 16 + l16];
    if (proj == 0) {
        #pragma unroll
        for (int nt = 0; nt < 4; ++nt) bias[nt] *= invt;   // prefold: e = expf(fma(acc, invt, bias))
    }

    float4v Tac[4];
    #pragma unroll
    for (int nt = 0; nt < 4; ++nt) Tac[nt] = (float4v){0.f, 0.f, 0.f, 0.f};
    float normAcc[4] = {0.f, 0.f, 0.f, 0.f};

    // fp32 x base for this tile (512 tokens x 256 ch)
    const float4v* xg4 = (const float4v*)(x + (long)tile * 512 * 256);

    // ---- prologue: stage chunk 0 into XS[0].  (R8 verbatim)
    // float4 #i of thread t = 4 consecutive ch of token (i*4 + wv), ch0 = lane*4.
    {
        float4v xs[8];
        #pragma unroll
        for (int i = 0; i < 8; ++i) xs[i] = xg4[i * 256 + tid];
        #pragma unroll
        for (int i = 0; i < 8; ++i) {
            uint2v p;
            p.x = pack2(xs[i].x, xs[i].y);
            p.y = pack2(xs[i].z, xs[i].w);
            *(uint2v*)(&XS[0][(i * 4 + wv) * XP + lane * 4]) = p;
        }
    }
    __syncthreads();

    for (int c = 0; c < 16; ++c) {
        const int wbuf = c & 1, rbuf = wbuf ^ 1;

        // A-frags from the x-stage: token = tw*16+l16, ch = ks*32+quad*8+j.
        // 528B pitch -> per-quad-phase 2-way bank aliasing = free.
        short8 afr[8];
        #pragma unroll
        for (int ks = 0; ks < 8; ++ks)
            afr[ks] = *(const short8*)(&XS[wbuf][(tw * 16 + l16) * XP + ks * 32 + quad * 8]);

        // P1: [16 tok x 64 cols] += A(x) * B(w-AGPRs), K=256
        float4v acc[4];
        #pragma unroll
        for (int nt = 0; nt < 4; ++nt) acc[nt] = (float4v){0.f, 0.f, 0.f, 0.f};
        __builtin_amdgcn_s_setprio(1);
        #pragma unroll
        for (int ks = 0; ks < 8; ++ks) {
            #pragma unroll
            for (int nt = 0; nt < 4; ++nt)
                acc[nt] = __builtin_amdgcn_mfma_f32_16x16x32_bf16(afr[ks], wfr[nt][ks], acc[nt], 0, 0, 0);
        }
        __builtin_amdgcn_s_setprio(0);

        // issue next chunk's fp32 loads (afr now dead -> regs reuse);
        // latency hidden behind P3 + P2.  (R8 verbatim)
        float4v xst[8];
        if (c < 15) {
            #pragma unroll
            for (int i = 0; i < 8; ++i)
                xst[i] = xg4[(c + 1) * 2048 + i * 256 + tid];
        }

        // P3 (skewed): T[s][d] += w^T fx over PREVIOUS chunk's 32 tokens.
        if (c > 0) {
            short8 a = *(const short8*)(&wT[rbuf][(wv * 16 + l16) * MP + quad * 8]);
            __builtin_amdgcn_s_setprio(1);
            #pragma unroll
            for (int nt = 0; nt < 4; ++nt) {
                short8 bf = *(const short8*)(&fT[rbuf][(nt * 16 + l16) * MP + quad * 8]);
                Tac[nt] = __builtin_amdgcn_mfma_f32_16x16x32_bf16(a, bf, Tac[nt], 0, 0, 0);
            }
            __builtin_amdgcn_s_setprio(0);
        }

        // P2: softmax / bias -> transposed bf16 into wbuf.
        // C layout: col=l16+16*nt, row=quad*4+rr -> token = tw*16+quad*4+rr
        if (proj == 0) {
            float e[4][4];
            #pragma unroll
            for (int nt = 0; nt < 4; ++nt)
                #pragma unroll
                for (int rr = 0; rr < 4; ++rr)
                    e[nt][rr] = __expf(fmaf(acc[nt][rr], invt, bias[nt]));  // bias pre-scaled by invt
            #pragma unroll
            for (int rr = 0; rr < 4; ++rr) {
                float s = (e[0][rr] + e[1][rr]) + (e[2][rr] + e[3][rr]);
                s += __shfl_xor(s, 1); s += __shfl_xor(s, 2);
                s += __shfl_xor(s, 4); s += __shfl_xor(s, 8);
                float inv = __builtin_amdgcn_rcpf(s);   // ~1ulp; weights ~1e-2, threshold 3e-3
                e[0][rr] *= inv; e[1][rr] *= inv; e[2][rr] *= inv; e[3][rr] *= inv;
            }
            #pragma unroll
            for (int nt = 0; nt < 4; ++nt) {
                normAcc[nt] += e[nt][0] + e[nt][1] + e[nt][2] + e[nt][3];
                uint2v p;
                p.x = pack2(e[nt][0], e[nt][1]);
                p.y = pack2(e[nt][2], e[nt][3]);
                *(uint2v*)(&wT[wbuf][(nt * 16 + l16) * MP + tw * 16 + quad * 4]) = p;
            }
        } else {
            #pragma unroll
            for (int nt = 0; nt < 4; ++nt) {
                uint2v p;
                p.x = pack2(acc[nt][0] + bias[nt], acc[nt][1] + bias[nt]);
                p.y = pack2(acc[nt][2] + bias[nt], acc[nt][3] + bias[nt]);
                *(uint2v*)(&fT[wbuf][(nt * 16 + l16) * MP + tw * 16 + quad * 4]) = p;
            }
        }

        // stage next chunk into the buffer this chunk just consumed  (R8 verbatim)
        if (c < 15) {
            #pragma unroll
            for (int i = 0; i < 8; ++i) {
                uint2v p;
                p.x = pack2(xst[i].x, xst[i].y);
                p.y = pack2(xst[i].z, xst[i].w);
                *(uint2v*)(&XS[rbuf][(i * 4 + wv) * XP + lane * 4]) = p;
            }
        }

        __syncthreads();   // single barrier per chunk (covers wT/fT and XS)
    }

    // final P3 on the last written buffer (chunk 15 -> buf 1)
    {
        short8 a = *(const short8*)(&wT[1][(wv * 16 + l16) * MP + quad * 8]);
        #pragma unroll
        for (int nt = 0; nt < 4; ++nt) {
            short8 bf = *(const short8*)(&fT[1][(nt * 16 + l16) * MP + quad * 8]);
            Tac[nt] = __builtin_amdgcn_mfma_f32_16x16x32_bf16(a, bf, Tac[nt], 0, 0, 0);
        }
    }

    // epilogue: atomics into global accumulators
    const int basehs = (batch * 8 + head) * 64;
    #pragma unroll
    for (int nt = 0; nt < 4; ++nt) {
        #pragma unroll
        for (int rr = 0; rr < 4; ++rr) {
            int s = wv * 16 + quad * 4 + rr;
            int d = nt * 16 + l16;
            atomicAdd(&Tg[(basehs + s) * 64 + d], Tac[nt][rr]);
        }
    }
    if (proj == 0) {
        #pragma unroll
        for (int nt = 0; nt < 4; ++nt) {
            float v = normAcc[nt];
            v += __shfl_xor(v, 16);
            v += __shfl_xor(v, 32);
            if (quad == 0) atomicAdd(&ng[basehs + nt * 16 + l16], v);
        }
    }
}

// ---------------- finalize ----------------
__global__ void msfe_final(const float* __restrict__ Tg, const float* __restrict__ ng,
                           float* __restrict__ out) {
    int i = blockIdx.x * 256 + threadIdx.x;
    out[i] = Tg[i] / (ng[i >> 6] + 0.01f);
}

extern "C" void kernel_launch(void* const* d_in, const int* in_sizes, int n_in,
                              void* d_out, int out_size, void* d_ws, size_t ws_size,
                              hipStream_t stream) {
    const float* x       = (const float*)d_in[0];
    const float* Wx      = (const float*)d_in[1];
    const float* bx      = (const float*)d_in[2];
    const float* Wfx     = (const float*)d_in[3];
    const float* bfx     = (const float*)d_in[4];
    const float* Wslice  = (const float*)d_in[5];
    const float* bslice  = (const float*)d_in[6];
    const float* temp    = (const float*)d_in[7];

    char* ws = (char*)d_ws;
    unsigned short* WtF = (unsigned short*)ws;       //  524,288 B
    float* bc = (float*)(ws + 524288);               //    2,048 B
    float* Tg = (float*)(ws + 526336);               //  262,144 B
    float* ng = (float*)(ws + 788480);               //    4,096 B

    hipMemsetAsync(Tg, 0, 262144 + 4096, stream);   // Tg+ng contiguous
    msfe_prep4<<<321, 256, 0, stream>>>(Wx, bx, Wfx, Wslice, bslice, WtF, bc);
    msfe_main9<<<2048, 256, 0, stream>>>(x, WtF, bc, bfx, temp, Tg, ng);
    msfe_final<<<256, 256, 0, stream>>>(Tg, ng, (float*)d_out);
}

// Round 6
// 309.136 us; speedup vs baseline: 1.0074x; 1.0074x over previous
//
#include <hip/hip_runtime.h>
#include <hip/hip_bf16.h>

// MultiScaleFeatureExtractor on MI355X (gfx950) — Round 12
// Math restructuring (unchanged):
//   logits = x @ (Wx@Wslice) + (bx@Wslice + bslice)      (px never materialized)
//   out[s,d] = (sum_n w[n,s]*fx[n,d]) / (sum_n w[n,s] + 0.01)
// R12 vs R11 (counter-driven):
//   - R11 closed the bisection: the b128 uint4v staging remap was the R9/R10
//     bug; the DPP rotate-reduce was innocent. R11 passed at main=163us.
//   - Occupancy is register-locked: 124 VGPR + 128 weight AGPRs = 252/256.
//     Only register-NEUTRAL critical-path shavers are legal (any +5 VGPR
//     halves occupancy). The proj0 wave's softmax chain (16 exp + 4-level
//     __shfl_xor reduce) gates the per-chunk barrier for all 4 waves.
//   - R12: (a) retest DPP row_ror rotate-reduce (VALU ~8cy/step) in place of
//     __shfl_xor (ds_swizzle ~30-60cy/step if LDS-lowered) -- clean isolated
//     change this time; (b) fold log2e into invt/bias so softmax is
//     exp2f(fma()) (drops the v_mul hidden in __expf). Both 1:1 reg-neutral.
//
// ws layout (NEED = 792,576 B):
//   [0,      524288)  WtF  bf16 B-frags [proj(2)][head(8)][nt(4)][ks(8)][lane(64)][j(8)]
//   [524288, 526336)  bc   f32 [512]
//   [526336, 788480)  Tg   f32 [B*8*64*64]
//   [788480, 792576)  ng   f32 [B*8*64]

typedef __attribute__((ext_vector_type(8))) short short8;
typedef __attribute__((ext_vector_type(4))) short short4v;
typedef __attribute__((ext_vector_type(4))) float float4v;
typedef __attribute__((ext_vector_type(2))) unsigned int uint2v;

#define MP 36        // wT/fT pitch: 32-token rows + 4 pad shorts (R4 measured 0 conflicts)
#define XP 264       // XS pitch in shorts: 528B rows (16B multiple; l16-lane frag reads 2-way = free)

// 16-lane rotate-accumulate on the VALU (DPP ROW_ROR:n = ctrl 0x120|n).
// After ror8,ror4,ror2,ror1 accumulation every lane of the row holds the row sum.
#define DPP_ADD(s, ctrl)                                                     \
    s += __int_as_float(__builtin_amdgcn_mov_dpp(__float_as_int(s), ctrl,    \
                                                 0xF, 0xF, true))

__device__ __forceinline__ unsigned short f2bf(float f) {
    union { float f; unsigned int u; } v; v.f = f;
    unsigned int r = (v.u + 0x7FFFu + ((v.u >> 16) & 1u)) >> 16;  // RNE
    return (unsigned short)r;
}

__device__ __forceinline__ unsigned int pack2(float a, float b) {
    __hip_bfloat162 h = __float22bfloat162_rn(float2{a, b});
    union { __hip_bfloat162 h; unsigned int u; } cv; cv.h = h;
    return cv.u;   // low 16 = a, high 16 = b
}

// ---- prep4: fold Wx@Wslice + reformat Wfx into B-frag order; compute bc. (R6, unchanged)
__global__ __launch_bounds__(256)
void msfe_prep4(const float* __restrict__ Wx, const float* __restrict__ bx,
                const float* __restrict__ Wfx,
                const float* __restrict__ Wslice, const float* __restrict__ bslice,
                unsigned short* __restrict__ WtF, float* __restrict__ bcv) {
    const int b = blockIdx.x, t = threadIdx.x;
    if (b < 256) {
        const int head = b >> 5, oct = b & 31;
        __shared__ float Wsl[64 * 65];          // [d][s] +1 pad
        __shared__ float WxS[8 * 64];           // [j][d]
        __shared__ unsigned short stg[8 * 64];  // [j][s]
        #pragma unroll
        for (int i = 0; i < 16; ++i) {          // Wslice: 4096 floats, coalesced
            int idx = i * 256 + t; int d = idx >> 6, s = idx & 63;
            Wsl[d * 65 + s] = Wslice[idx];
        }
        #pragma unroll
        for (int i = 0; i < 2; ++i) {           // 8 Wx rows x 64 ch, coalesced 256B rows
            int idx = i * 256 + t; int j = idx >> 6, d = idx & 63;
            WxS[j * 64 + d] = Wx[(long)(oct * 8 + j) * 512 + head * 64 + d];
        }
        __syncthreads();
        const int s = t & 63;
        #pragma unroll
        for (int rep = 0; rep < 2; ++rep) {
            int j = (t >> 6) + rep * 4;         // wave-uniform j
            float a0 = 0.f, a1 = 0.f, a2 = 0.f, a3 = 0.f;
            #pragma unroll
            for (int d = 0; d < 64; d += 4) {   // WxS broadcast (free), Wsl 2-way (free)
                a0 += WxS[j * 64 + d]     * Wsl[(d)     * 65 + s];
                a1 += WxS[j * 64 + d + 1] * Wsl[(d + 1) * 65 + s];
                a2 += WxS[j * 64 + d + 2] * Wsl[(d + 2) * 65 + s];
                a3 += WxS[j * 64 + d + 3] * Wsl[(d + 3) * 65 + s];
            }
            stg[j * 64 + s] = f2bf((a0 + a1) + (a2 + a3));
        }
        __syncthreads();
        if (t < 64) {
            int nt = t >> 4, l16 = t & 15;
            int ks = oct >> 2, quad = oct & 3;
            int lane = quad * 16 + l16;
            short8 o;
            #pragma unroll
            for (int j = 0; j < 8; ++j) o[j] = (short)stg[j * 64 + nt * 16 + l16];
            *(short8*)(WtF + ((((long)(0 * 8 + head) * 4 + nt) * 8 + ks) * 64 + lane) * 8) = o;
        }
    } else if (b < 320) {
        const int head = (b - 256) >> 3, ks = (b - 256) & 7;
        const int nt = t >> 6, lane = t & 63;
        const int quad = lane >> 4, l16 = lane & 15;
        short8 o;
        #pragma unroll
        for (int j = 0; j < 8; ++j)             // 4x64B segments per instr
            o[j] = (short)f2bf(Wfx[(long)(ks * 32 + quad * 8 + j) * 512 + head * 64 + nt * 16 + l16]);
        *(short8*)(WtF + ((((long)(1 * 8 + head) * 4 + nt) * 8 + ks) * 64 + lane) * 8) = o;
    } else {
        #pragma unroll
        for (int p = 0; p < 2; ++p) {
            int j = t + p * 256;
            int h = j >> 6, s = j & 63;
            float bsum = bslice[s];
            for (int d = 0; d < 64; ++d) bsum += bx[h * 64 + d] * Wslice[d * 64 + s];
            bcv[j] = bsum;
        }
    }
}

// ---- main10: 2048 blocks x 256 thr (4 waves), 512-token tiles, 16 x 32-token chunks.
// Weights pinned in AGPRs ("+a"); x staged fp32->bf16 in-block (R8 staging, verbatim).
// R12 deltas: DPP rotate-reduce softmax, exp2 prefold (log2e folded into invt/bias).
__global__ __launch_bounds__(256, 2)
void msfe_main10(const float* __restrict__ x,
                 const unsigned short* __restrict__ WtF,
                 const float* __restrict__ bcv,
                 const float* __restrict__ bfx,
                 const float* __restrict__ temperature,
                 float* __restrict__ Tg, float* __restrict__ ng) {
    __shared__ unsigned short wT[2][64 * MP];              // [s][token] bf16, double-buffered
    __shared__ unsigned short fT[2][64 * MP];              // [d][token]
    __shared__ __align__(16) unsigned short XS[2][32 * XP];// [token][ch] bf16 x-stage, dbuf

    const int tid  = threadIdx.x;
    const int lane = tid & 63;
    const int wv   = tid >> 6;    // 0..3
    const int quad = lane >> 4;
    const int l16  = lane & 15;

    // swizzle: a tile's 8 head-blocks land on one XCD in the same dispatch round
    const int bidx = blockIdx.x;                     // 0..2047
    const int tile = (bidx >> 6) * 8 + (bidx & 7);   // 0..255 (512 tokens each)
    const int head = (bidx >> 3) & 7;
    const int batch = tile >> 7;

    const int proj = wv >> 1;   // waves 0,1: logits+softmax; 2,3: fx
    const int tw   = wv & 1;    // 16-token sub-tile within 32-token chunk

    // ---- weight fragments -> AGPRs, pinned (R6: "+a" leaves VGPRs for loads).
    short8 wfr[4][8];
    {
        const unsigned short* wb = WtF + (((long)(proj * 8 + head) * 4) * 8) * 512 + (long)lane * 8;
        #pragma unroll
        for (int nt = 0; nt < 4; ++nt)
            #pragma unroll
            for (int ks = 0; ks < 8; ++ks)
                wfr[nt][ks] = *(const short8*)(wb + (nt * 8 + ks) * 512);
    }
    #pragma unroll
    for (int nt = 0; nt < 4; ++nt)
        #pragma unroll
        for (int ks = 0; ks < 8; ++ks)
            asm volatile("" : "+a"(wfr[nt][ks]));

    float tmp = temperature[head];
    tmp = fminf(fmaxf(tmp, 0.5f), 5.0f);
    const float invt = 1.0f / tmp;
    const float invt2 = invt * 1.44269504088896f;   // fold log2e: exp(z) = exp2(z*log2e)

    float bias[4];
    #pragma unroll
    for (int nt = 0; nt < 4; ++nt)
        bias[nt] = (proj == 0 ? bcv : bfx)[head * 64 + nt * 16 + l16];
    if (proj == 0) {
        #pragma unroll
        for (int nt = 0; nt < 4; ++nt) bias[nt] *= invt2;  // e = exp2f(fma(acc, invt2, bias))
    }

    float4v Tac[4];
    #pragma unroll
    for (int nt = 0; nt < 4; ++nt) Tac[nt] = (float4v){0.f, 0.f, 0.f, 0.f};
    float normAcc[4] = {0.f, 0.f, 0.f, 0.f};

    // fp32 x base for this tile (512 tokens x 256 ch)
    const float4v* xg4 = (const float4v*)(x + (long)tile * 512 * 256);

    // ---- prologue: stage chunk 0 into XS[0].  (R8 verbatim)
    // float4 #i of thread t = 4 consecutive ch of token (i*4 + wv), ch0 = lane*4.
    {
        float4v xs[8];
        #pragma unroll
        for (int i = 0; i < 8; ++i) xs[i] = xg4[i * 256 + tid];
        #pragma unroll
        for (int i = 0; i < 8; ++i) {
            uint2v p;
            p.x = pack2(xs[i].x, xs[i].y);
            p.y = pack2(xs[i].z, xs[i].w);
            *(uint2v*)(&XS[0][(i * 4 + wv) * XP + lane * 4]) = p;
        }
    }
    __syncthreads();

    for (int c = 0; c < 16; ++c) {
        const int wbuf = c & 1, rbuf = wbuf ^ 1;

        // A-frags from the x-stage: token = tw*16+l16, ch = ks*32+quad*8+j.
        // 528B pitch -> per-quad-phase 2-way bank aliasing = free.
        short8 afr[8];
        #pragma unroll
        for (int ks = 0; ks < 8; ++ks)
            afr[ks] = *(const short8*)(&XS[wbuf][(tw * 16 + l16) * XP + ks * 32 + quad * 8]);

        // P1: [16 tok x 64 cols] += A(x) * B(w-AGPRs), K=256
        float4v acc[4];
        #pragma unroll
        for (int nt = 0; nt < 4; ++nt) acc[nt] = (float4v){0.f, 0.f, 0.f, 0.f};
        __builtin_amdgcn_s_setprio(1);
        #pragma unroll
        for (int ks = 0; ks < 8; ++ks) {
            #pragma unroll
            for (int nt = 0; nt < 4; ++nt)
                acc[nt] = __builtin_amdgcn_mfma_f32_16x16x32_bf16(afr[ks], wfr[nt][ks], acc[nt], 0, 0, 0);
        }
        __builtin_amdgcn_s_setprio(0);

        // issue next chunk's fp32 loads (afr now dead -> regs reuse);
        // latency hidden behind P3 + P2.  (R8 verbatim)
        float4v xst[8];
        if (c < 15) {
            #pragma unroll
            for (int i = 0; i < 8; ++i)
                xst[i] = xg4[(c + 1) * 2048 + i * 256 + tid];
        }

        // P3 (skewed): T[s][d] += w^T fx over PREVIOUS chunk's 32 tokens.
        if (c > 0) {
            short8 a = *(const short8*)(&wT[rbuf][(wv * 16 + l16) * MP + quad * 8]);
            __builtin_amdgcn_s_setprio(1);
            #pragma unroll
            for (int nt = 0; nt < 4; ++nt) {
                short8 bf = *(const short8*)(&fT[rbuf][(nt * 16 + l16) * MP + quad * 8]);
                Tac[nt] = __builtin_amdgcn_mfma_f32_16x16x32_bf16(a, bf, Tac[nt], 0, 0, 0);
            }
            __builtin_amdgcn_s_setprio(0);
        }

        // P2: softmax / bias -> transposed bf16 into wbuf.
        // C layout: col=l16+16*nt, row=quad*4+rr -> token = tw*16+quad*4+rr
        if (proj == 0) {
            float e[4][4];
            #pragma unroll
            for (int nt = 0; nt < 4; ++nt)
                #pragma unroll
                for (int rr = 0; rr < 4; ++rr)
                    e[nt][rr] = exp2f(fmaf(acc[nt][rr], invt2, bias[nt]));  // log2e prefolded
            #pragma unroll
            for (int rr = 0; rr < 4; ++rr) {
                float s = (e[0][rr] + e[1][rr]) + (e[2][rr] + e[3][rr]);
                // 16-lane rotate-accumulate on the VALU (no LDS pipe):
                DPP_ADD(s, 0x128);   // += ror8
                DPP_ADD(s, 0x124);   // += ror4
                DPP_ADD(s, 0x122);   // += ror2
                DPP_ADD(s, 0x121);   // += ror1
                float inv = __builtin_amdgcn_rcpf(s);   // ~1ulp; weights ~1e-2, threshold 3e-3
                e[0][rr] *= inv; e[1][rr] *= inv; e[2][rr] *= inv; e[3][rr] *= inv;
            }
            #pragma unroll
            for (int nt = 0; nt < 4; ++nt) {
                normAcc[nt] += e[nt][0] + e[nt][1] + e[nt][2] + e[nt][3];
                uint2v p;
                p.x = pack2(e[nt][0], e[nt][1]);
                p.y = pack2(e[nt][2], e[nt][3]);
                *(uint2v*)(&wT[wbuf][(nt * 16 + l16) * MP + tw * 16 + quad * 4]) = p;
            }
        } else {
            #pragma unroll
            for (int nt = 0; nt < 4; ++nt) {
                uint2v p;
                p.x = pack2(acc[nt][0] + bias[nt], acc[nt][1] + bias[nt]);
                p.y = pack2(acc[nt][2] + bias[nt], acc[nt][3] + bias[nt]);
                *(uint2v*)(&fT[wbuf][(nt * 16 + l16) * MP + tw * 16 + quad * 4]) = p;
            }
        }

        // stage next chunk into the buffer this chunk just consumed  (R8 verbatim)
        if (c < 15) {
            #pragma unroll
            for (int i = 0; i < 8; ++i) {
                uint2v p;
                p.x = pack2(xst[i].x, xst[i].y);
                p.y = pack2(xst[i].z, xst[i].w);
                *(uint2v*)(&XS[rbuf][(i * 4 + wv) * XP + lane * 4]) = p;
            }
        }

        __syncthreads();   // single barrier per chunk (covers wT/fT and XS)
    }

    // final P3 on the last written buffer (chunk 15 -> buf 1)
    {
        short8 a = *(const short8*)(&wT[1][(wv * 16 + l16) * MP + quad * 8]);
        #pragma unroll
        for (int nt = 0; nt < 4; ++nt) {
            short8 bf = *(const short8*)(&fT[1][(nt * 16 + l16) * MP + quad * 8]);
            Tac[nt] = __builtin_amdgcn_mfma_f32_16x16x32_bf16(a, bf, Tac[nt], 0, 0, 0);
        }
    }

    // epilogue: atomics into global accumulators
    const int basehs = (batch * 8 + head) * 64;
    #pragma unroll
    for (int nt = 0; nt < 4; ++nt) {
        #pragma unroll
        for (int rr = 0; rr < 4; ++rr) {
            int s = wv * 16 + quad * 4 + rr;
            int d = nt * 16 + l16;
            atomicAdd(&Tg[(basehs + s) * 64 + d], Tac[nt][rr]);
        }
    }
    if (proj == 0) {
        #pragma unroll
        for (int nt = 0; nt < 4; ++nt) {
            float v = normAcc[nt];
            v += __shfl_xor(v, 16);
            v += __shfl_xor(v, 32);
            if (quad == 0) atomicAdd(&ng[basehs + nt * 16 + l16], v);
        }
    }
}

// ---------------- finalize ----------------
__global__ void msfe_final(const float* __restrict__ Tg, const float* __restrict__ ng,
                           float* __restrict__ out) {
    int i = blockIdx.x * 256 + threadIdx.x;
    out[i] = Tg[i] / (ng[i >> 6] + 0.01f);
}

extern "C" void kernel_launch(void* const* d_in, const int* in_sizes, int n_in,
                              void* d_out, int out_size, void* d_ws, size_t ws_size,
                              hipStream_t stream) {
    const float* x       = (const float*)d_in[0];
    const float* Wx      = (const float*)d_in[1];
    const float* bx      = (const float*)d_in[2];
    const float* Wfx     = (const float*)d_in[3];
    const float* bfx     = (const float*)d_in[4];
    const float* Wslice  = (const float*)d_in[5];
    const float* bslice  = (const float*)d_in[6];
    const float* temp    = (const float*)d_in[7];

    char* ws = (char*)d_ws;
    unsigned short* WtF = (unsigned short*)ws;       //  524,288 B
    float* bc = (float*)(ws + 524288);               //    2,048 B
    float* Tg = (float*)(ws + 526336);               //  262,144 B
    float* ng = (float*)(ws + 788480);               //    4,096 B

    hipMemsetAsync(Tg, 0, 262144 + 4096, stream);   // Tg+ng contiguous
    msfe_prep4<<<321, 256, 0, stream>>>(Wx, bx, Wfx, Wslice, bslice, WtF, bc);
    msfe_main10<<<2048, 256, 0, stream>>>(x, WtF, bc, bfx, temp, Tg, ng);
    msfe_final<<<256, 256, 0, stream>>>(Tg, ng, (float*)d_out);
}